// Round 13
// baseline (204.695 us; speedup 1.0000x reference)
//
#include <hip/hip_runtime.h>
#include <math.h>

#define BB 512
#define NN 1000
#define DD 128
#define HH 8
#define TILE 125   // 8 tiles of 125 rows

__device__ __forceinline__ bool mask_feasible(const void* mask, int flag, int idx) {
    if (flag == 1) return ((const int*)mask)[idx] != 0;
    if (flag == 2) return ((const float*)mask)[idx] != 0.0f;
    return ((const unsigned char*)mask)[idx] != 0;
}

__device__ __forceinline__ float rdl(float v, int srclane) {
    return __int_as_float(__builtin_amdgcn_readlane(__float_as_int(v), srclane));
}

// Detect action_mask storage dtype from its first 64 32-bit words.
__global__ void k0_detect(const unsigned int* __restrict__ m, int* __restrict__ flag) {
    int t = threadIdx.x;
    unsigned int w = m[t];
    unsigned long long bi = __ballot(w <= 1u);
    unsigned long long bf = __ballot(w == 0u || w == 0x3F800000u);
    if (t == 0) {
        int f = 0;
        if (bi == ~0ull) f = 1;
        else if (bf == ~0ull) f = 2;
        *flag = f;
    }
}

// Fused mega-kernel: mean -> q -> Afold -> flash(no-max softmax) -> glimpse -> logits.
// One block of 256 per b (R4/R12's measured-best kB config). Single-arg
// launch_bounds ONLY (R5: the 2nd arg acts as min-BLOCKS/CU, caps VGPR at 64,
// 518 MB scratch spill). emb is read HBM-cold exactly once (mean pass);
// flash + logits re-reads hit L2 (512KB/block x 8 blocks/XCD = 4MB) or L3.
__global__ __launch_bounds__(256) void kMega(
    const float* __restrict__ emb, const float* __restrict__ ctx,
    const float* __restrict__ W_fixed, const float* __restrict__ W_step,
    const float* __restrict__ W_node, const float* __restrict__ W_out,
    const void* __restrict__ mask, const int* __restrict__ flagp,
    float* __restrict__ out) {
    int b = blockIdx.x, t = threadIdx.x;
    int flag = *flagp;
    int lane = t & 63;
    int hq = (t >> 7) * 4;               // waves 0,1 -> h0..3 ; 2,3 -> h4..7
    int n = t & 127;                     // compat row (valid < TILE)
    int c4 = t & 31, jr = t >> 5;        // accumulate role (jr 0..7)

    __shared__ float4 tile4[128][32];    // 64 KB: mean-red / Afold / staged tile / j-reduce
    __shared__ float cbuf[128][8];       // 4 KB: prologue mean/cld/q ; then p values
    __shared__ float wemb_s[8][128];     // 4 KB
    __shared__ float small[3 * DD];      // hl / gl / g2
    __shared__ float zl[HH];

    const float4* embB4 = (const float4*)(emb + (size_t)b * NN * DD);
    const int mbase = b * NN;
    float* cb = (float*)cbuf;            // flat view for prologue

    // ---- P0: mean over N (the one HBM-cold pass over this block's rows) ----
    {
        float4 acc = make_float4(0.f, 0.f, 0.f, 0.f);
        for (int nn = jr; nn < NN; nn += 8) {
            float4 v = embB4[nn * 32 + c4];
            acc.x += v.x; acc.y += v.y; acc.z += v.z; acc.w += v.w;
        }
        float4* red = (float4*)tile4;
        red[t] = acc;
        __syncthreads();
        for (int s = 4; s >= 1; s >>= 1) {
            if (jr < s) {
                float4 o = red[t + s * 32], m = red[t];
                m.x += o.x; m.y += o.y; m.z += o.z; m.w += o.w;
                red[t] = m;
            }
            __syncthreads();
        }
        if (t < 32) {
            float4 m = red[t];
            const float inv = 1.0f / (float)NN;
            ((float4*)cb)[t] = make_float4(m.x * inv, m.y * inv, m.z * inv, m.w * inv);
        }
        cb[128 + t] = ctx[b * 2 * DD + t];   // cld (256 floats at cb[128:384])
    }
    __syncthreads();
    // ---- P1: q = mean@W_fixed + ctx@W_step -> cb[384:512] ----
    if (t < 128) {
        float a = 0.f;
        for (int c = 0; c < DD; ++c)     a += cb[c] * W_fixed[c * DD + t];
        for (int c = 0; c < 2 * DD; ++c) a += cb[128 + c] * W_step[c * DD + t];
        cb[384 + t] = a;
    }
    __syncthreads();
    // ---- P2: Afold[c][h] -> first 1024 floats of tile4 ----
    {
        float* Af = (float*)tile4;
        if (t < 128) {
            const float* wrow = W_node + (size_t)t * 3 * DD;   // Wk cols [0,128)
            for (int h = 0; h < HH; ++h) {
                float a = 0.f;
#pragma unroll
                for (int d0 = 0; d0 < 16; ++d0) a += wrow[h * 16 + d0] * cb[384 + h * 16 + d0];
                Af[t * 8 + h] = 0.25f * a;   // 1/sqrt(dk) folded
            }
        }
    }
    __syncthreads();
    // ---- A lane-distributed regs: lane l holds A[l][hq+h'], A[64+l][hq+h'] ----
    const float* Af = (const float*)tile4;
    float a0l = Af[lane * 8 + hq + 0], a1l = Af[lane * 8 + hq + 1];
    float a2l = Af[lane * 8 + hq + 2], a3l = Af[lane * 8 + hq + 3];
    float a0h = Af[(64 + lane) * 8 + hq + 0], a1h = Af[(64 + lane) * 8 + hq + 1];
    float a2h = Af[(64 + lane) * 8 + hq + 2], a3h = Af[(64 + lane) * 8 + hq + 3];
    __syncthreads();                      // tile4 free for staging

    float4 wacc[8];
#pragma unroll
    for (int h = 0; h < HH; ++h) wacc[h] = make_float4(0.f, 0.f, 0.f, 0.f);
    float zrun = 0.f;                    // meaningful on t<8 only

    // ---- flash loop (R12-validated): stage -> p=exp(compat) -> z -> accumulate ----
    for (int tile = 0; tile < 8; ++tile) {
        int n0 = tile * TILE;
#pragma unroll
        for (int idx = 0; idx < 16; ++idx) {
            int i = t + idx * 256;
            if (i < TILE * 32) {
                int r = i >> 5, c = i & 31;
                tile4[r][c ^ (r & 31)] = embB4[n0 * 32 + i];
            }
        }
        __syncthreads();
        if (n < TILE) {
            int sw = n & 31;
            float4 s = make_float4(0.f, 0.f, 0.f, 0.f);
#pragma unroll 4
            for (int k = 0; k < 16; ++k) {          // cols 0..63
                float4 e = tile4[n][k ^ sw];
                int c = k * 4;
                s.x += e.x * rdl(a0l, c) + e.y * rdl(a0l, c + 1) + e.z * rdl(a0l, c + 2) + e.w * rdl(a0l, c + 3);
                s.y += e.x * rdl(a1l, c) + e.y * rdl(a1l, c + 1) + e.z * rdl(a1l, c + 2) + e.w * rdl(a1l, c + 3);
                s.z += e.x * rdl(a2l, c) + e.y * rdl(a2l, c + 1) + e.z * rdl(a2l, c + 2) + e.w * rdl(a2l, c + 3);
                s.w += e.x * rdl(a3l, c) + e.y * rdl(a3l, c + 1) + e.z * rdl(a3l, c + 2) + e.w * rdl(a3l, c + 3);
            }
#pragma unroll 4
            for (int k = 16; k < 32; ++k) {         // cols 64..127
                float4 e = tile4[n][k ^ sw];
                int c = k * 4 - 64;
                s.x += e.x * rdl(a0h, c) + e.y * rdl(a0h, c + 1) + e.z * rdl(a0h, c + 2) + e.w * rdl(a0h, c + 3);
                s.y += e.x * rdl(a1h, c) + e.y * rdl(a1h, c + 1) + e.z * rdl(a1h, c + 2) + e.w * rdl(a1h, c + 3);
                s.z += e.x * rdl(a2h, c) + e.y * rdl(a2h, c + 1) + e.z * rdl(a2h, c + 2) + e.w * rdl(a2h, c + 3);
                s.w += e.x * rdl(a3h, c) + e.y * rdl(a3h, c + 1) + e.z * rdl(a3h, c + 2) + e.w * rdl(a3h, c + 3);
            }
            bool feas = mask_feasible(mask, flag, mbase + n0 + n);
            float4 p = make_float4(0.f, 0.f, 0.f, 0.f);
            if (feas) {
                p.x = __expf(s.x); p.y = __expf(s.y);
                p.z = __expf(s.z); p.w = __expf(s.w);
            }
            *(float4*)&cbuf[n][hq] = p;
        }
        __syncthreads();
        if (t < 64) {   // z mini-reduce on wave 0
            int h = t & 7, seg = t >> 3;
            float z = 0.f;
            for (int nn = seg; nn < TILE; nn += 8) z += cbuf[nn][h];
            z += __shfl_xor(z, 8);
            z += __shfl_xor(z, 16);
            z += __shfl_xor(z, 32);
            if (t < 8) zrun += z;
        }
        for (int nn = jr; nn < TILE; nn += 8) {
            float4 e = tile4[nn][c4 ^ (nn & 31)];
            float4 pA = *(const float4*)&cbuf[nn][0];
            float4 pB = *(const float4*)&cbuf[nn][4];
            wacc[0].x += pA.x * e.x; wacc[0].y += pA.x * e.y; wacc[0].z += pA.x * e.z; wacc[0].w += pA.x * e.w;
            wacc[1].x += pA.y * e.x; wacc[1].y += pA.y * e.y; wacc[1].z += pA.y * e.z; wacc[1].w += pA.y * e.w;
            wacc[2].x += pA.z * e.x; wacc[2].y += pA.z * e.y; wacc[2].z += pA.z * e.z; wacc[2].w += pA.z * e.w;
            wacc[3].x += pA.w * e.x; wacc[3].y += pA.w * e.y; wacc[3].z += pA.w * e.z; wacc[3].w += pA.w * e.w;
            wacc[4].x += pB.x * e.x; wacc[4].y += pB.x * e.y; wacc[4].z += pB.x * e.z; wacc[4].w += pB.x * e.w;
            wacc[5].x += pB.y * e.x; wacc[5].y += pB.y * e.y; wacc[5].z += pB.y * e.z; wacc[5].w += pB.y * e.w;
            wacc[6].x += pB.z * e.x; wacc[6].y += pB.z * e.y; wacc[6].z += pB.z * e.z; wacc[6].w += pB.z * e.w;
            wacc[7].x += pB.w * e.x; wacc[7].y += pB.w * e.y; wacc[7].z += pB.w * e.z; wacc[7].w += pB.w * e.w;
        }
        __syncthreads();   // tile4/cbuf dead before next stage
    }
    if (t < 8) zl[t] = zrun;
    // ---- j-reduce wemb partials (tile4 as [8][32][8] f4 scratch), normalize ----
    {
        float4* red = (float4*)&tile4[0][0];
#pragma unroll
        for (int h = 0; h < HH; ++h) red[(jr * 32 + c4) * 8 + h] = wacc[h];
        __syncthreads();
        int cc = t >> 3, hh = t & 7;
        float4 s = make_float4(0.f, 0.f, 0.f, 0.f);
#pragma unroll
        for (int jj = 0; jj < 8; ++jj) {
            float4 v = red[(jj * 32 + cc) * 8 + hh];
            s.x += v.x; s.y += v.y; s.z += v.z; s.w += v.w;
        }
        float inv = 1.0f / zl[hh];
        s.x *= inv; s.y *= inv; s.z *= inv; s.w *= inv;
        *(float4*)&wemb_s[hh][cc * 4] = s;
    }
    __syncthreads();
    // ---- glimpse tail ----
    if (t < 128) {
        int h = t >> 4;
        float a = 0.f;
        for (int c = 0; c < DD; ++c) a += wemb_s[h][c] * W_node[(size_t)c * 384 + 128 + t];
        small[t] = a;                          // hl
    }
    __syncthreads();
    if (t < 128) {
        float g = 0.f;
        for (int k = 0; k < DD; ++k) g += small[k] * W_out[k * DD + t];
        small[128 + t] = g;                    // gl
    }
    __syncthreads();
    if (t < 128) {
        float a3 = 0.f;
        const float* wr = W_node + (size_t)t * 384 + 256;   // Wl row t
        for (int d = 0; d < DD; ++d) a3 += wr[d] * small[128 + d];
        small[256 + t] = a3;                   // g2
    }
    __syncthreads();
    // ---- logits tail ----
    const float4* g2v = (const float4*)&small[256];
    for (int r = t; r < NN; r += 256) {
        const float4* row = embB4 + (size_t)r * 32;
        float acc = 0.f;
#pragma unroll 8
        for (int k = 0; k < 32; ++k) {
            float4 e = row[k], g = g2v[k];
            acc += e.x * g.x + e.y * g.y + e.z * g.z + e.w * g.w;
        }
        bool feas = mask_feasible(mask, flag, mbase + r);
        out[(size_t)mbase + r] = feas ? (10.0f * tanhf(acc * 0.08838834764831845f)) : -1.0e30f;
    }
}

extern "C" void kernel_launch(void* const* d_in, const int* in_sizes, int n_in,
                              void* d_out, int out_size, void* d_ws, size_t ws_size,
                              hipStream_t stream) {
    (void)in_sizes; (void)n_in; (void)out_size; (void)ws_size;
    const float* emb     = (const float*)d_in[0];
    const float* ctx     = (const float*)d_in[1];
    const float* W_node  = (const float*)d_in[2];
    const float* W_fixed = (const float*)d_in[3];
    const float* W_step  = (const float*)d_in[4];
    const float* W_out   = (const float*)d_in[5];
    const void*  mask    = d_in[6];
    float* out = (float*)d_out;

    int* flag = (int*)d_ws;
    k0_detect<<<1, 64, 0, stream>>>((const unsigned int*)mask, flag);
    kMega<<<BB, 256, 0, stream>>>(emb, ctx, W_fixed, W_step, W_node, W_out, mask, flag, out);
}